// Round 22
// baseline (262.911 us; speedup 1.0000x reference)
//
#include <hip/hip_runtime.h>
#include <hip/hip_bf16.h>

#define N_ROWS 200000
#define BM 32
#define NTILES 6250
#define TPB 4
#define NBLK ((NTILES + TPB - 1) / TPB)
#define NGRAPH 64
#define SSCALE 1.6666666666666667f
#define LOG2E 1.4426950408889634f

typedef __attribute__((ext_vector_type(8))) short short8;   // 8 bf16 (4 VGPRs)
typedef __attribute__((ext_vector_type(4))) float f32x4;    // MFMA C/D frag

__device__ __forceinline__ unsigned short f2bf(float f) {
    unsigned int u = __float_as_uint(f);
    u = (u + 0x7fffu + ((u >> 16) & 1u)) >> 16;   // RNE
    return (unsigned short)u;
}
__device__ __forceinline__ float bf2f(unsigned short v) {
    return __uint_as_float(((unsigned int)v) << 16);
}
__device__ __forceinline__ unsigned int cvt_pk_bf16(float lo, float hi) {
    unsigned int r;
    asm("v_cvt_pk_bf16_f32 %0, %1, %2" : "=v"(r) : "v"(lo), "v"(hi));
    return r;
}
// fast ScaledSiLU: s*SCALE * rcp(1 + exp2(-s*log2e))
__device__ __forceinline__ float ssilu_f(float s) {
    float e = __builtin_amdgcn_exp2f(-s * LOG2E);
    return s * SSCALE * __builtin_amdgcn_rcpf(1.0f + e);
}

// lgkmcnt-only barrier: LDS ops retired, global stores stay in flight
#define BAR_LGKM()  do { asm volatile("s_waitcnt lgkmcnt(0)" ::: "memory"); \
                         __builtin_amdgcn_s_barrier(); } while (0)

// ---- fused setup: LDS-tiled weight transpose x2, vc GEMV, sums zero + counts ----
__global__ __launch_bounds__(256) void setup_kernel(
        const float* __restrict__ Wn1, const float* __restrict__ Wn2,
        const float* __restrict__ vx, const float* __restrict__ bn1,
        const int* __restrict__ batch,
        unsigned short* __restrict__ wnt1x, unsigned short* __restrict__ wnt2,
        float* __restrict__ vc, float* __restrict__ sums,
        int* __restrict__ counts) {
    const int bid = blockIdx.x;
    const int t = threadIdx.x;
    if (bid < 32) {
        const float* W = (bid < 16) ? Wn1 : Wn2;
        unsigned short* out = (bid < 16) ? wnt1x : wnt2;
        const int tile = bid & 15;
        const int bi = (tile >> 2) * 64;   // k base
        const int bj = (tile & 3) * 64;    // n base
        __shared__ float lds[64][65];
        const int rr = t >> 4;             // 0..15
        const int cc = (t & 15) * 4;       // 0..60
        #pragma unroll
        for (int i = 0; i < 4; ++i) {
            int row = i * 16 + rr;         // k offset
            float4 v = *reinterpret_cast<const float4*>(&W[(bi + row) * 256 + bj + cc]);
            lds[row][cc] = v.x; lds[row][cc + 1] = v.y;
            lds[row][cc + 2] = v.z; lds[row][cc + 3] = v.w;
        }
        __syncthreads();
        #pragma unroll
        for (int i = 0; i < 4; ++i) {
            int nrow = i * 16 + rr;        // n offset
            ushort4 u;
            u.x = f2bf(lds[cc + 0][nrow]);
            u.y = f2bf(lds[cc + 1][nrow]);
            u.z = f2bf(lds[cc + 2][nrow]);
            u.w = f2bf(lds[cc + 3][nrow]);
            *reinterpret_cast<ushort4*>(&out[(bj + nrow) * 256 + bi + cc]) = u;
        }
    } else if (bid < 32 + NGRAPH) {
        int b = bid - 32;
        __shared__ float vrow[256];
        vrow[t] = vx[b * 256 + t];
        __syncthreads();
        float a = bn1[t];
        #pragma unroll 8
        for (int k = 0; k < 256; ++k) a = fmaf(vrow[k], Wn1[(256 + k) * 256 + t], a);
        vc[b * 256 + t] = a;
    } else {
        int b = bid - 32 - NGRAPH;
        sums[b * 256 + t] = 0.0f;
        if (t == 0) {
            int lo = 0, hi = N_ROWS;
            while (lo < hi) { int m = (lo + hi) >> 1; if (batch[m] < b) lo = m + 1; else hi = m; }
            int lb = lo;
            lo = 0; hi = N_ROWS;
            while (lo < hi) { int m = (lo + hi) >> 1; if (batch[m] < b + 1) lo = m + 1; else hi = m; }
            counts[b] = lo - lb;
        }
    }
}

// ---- main fused node-MLP kernel: 16 waves x 16 cols, 64 weight regs/thread,
//      transposed mfma output, 16-row XOR swizzle; hoisted h1 loads,
//      uniform-branch pooling ----
__global__ __launch_bounds__(1024, 4) void node_kernel(
    const float* __restrict__ x, const int* __restrict__ batch,
    const unsigned short* __restrict__ wnt1x,  // [256][256] bf16, x-half of Wn1, N-major
    const float* __restrict__ vc,              // [64][256] per-graph bias (incl bn1)
    const unsigned short* __restrict__ wnt2,   // [256][256] bf16, N-major
    const float* __restrict__ bn2,
    float* __restrict__ hout, float* __restrict__ sums)
{
    __shared__ unsigned short xa[2][BM * 256]; // x tiles bf16, swizzled (2x16 KB)
    __shared__ unsigned short hb[2][BM * 256]; // h1 tiles bf16, swizzled (2x16 KB)

    const int t = threadIdx.x;
    const int lane = t & 63;
    const int wave = t >> 6;          // 0..15
    const int lr = lane & 15;
    const int lg = lane >> 4;
    const int c = wave * 16 + lg * 4; // this lane's 4 output cols: c..c+3

    // ---- weight slices into registers (A-operand layout: lane&15 = weight col) ----
    short8 w1r[8], w2r[8];
    #pragma unroll
    for (int kk = 0; kk < 8; ++kk) {
        int off = (wave * 16 + lr) * 256 + kk * 32 + lg * 8;
        w1r[kk] = *reinterpret_cast<const short8*>(&wnt1x[off]);
        w2r[kk] = *reinterpret_cast<const short8*>(&wnt2[off]);
    }
    const float4 bn2v = *reinterpret_cast<const float4*>(&bn2[c]);

    const int tile0 = blockIdx.x * TPB;
    const int blk_r0 = tile0 * BM;
    const int blk_rlast = min(blk_r0 + TPB * BM, N_ROWS) - 1;
    const int g0 = batch[blk_r0];
    const bool blk_multi = (batch[blk_rlast] != g0);
    float pa[4] = {0.f, 0.f, 0.f, 0.f};   // pooled partials: graph g0
    float pb[4] = {0.f, 0.f, 0.f, 0.f};   // pooled partials: graph g0+1

    const f32x4 zero4 = {0.f, 0.f, 0.f, 0.f};

    // ---- prologue: load tile0's x into regs (32x256 f32 = 1024 thr x 2 float4) ----
    float4 vreg[2];
    {
        const float4* xp = reinterpret_cast<const float4*>(x + (size_t)tile0 * (BM * 256));
        #pragma unroll
        for (int i = 0; i < 2; ++i) vreg[i] = xp[t + i * 1024];
    }

    int cur = 0;
    #pragma unroll 1
    for (int it = 0; it < TPB; ++it) {
        const int tile = tile0 + it;
        if (tile >= NTILES) break;
        const int r0 = tile * BM;

        // ---- write staged regs -> xa[cur] as bf16 (16-row swizzle) ----
        #pragma unroll
        for (int i = 0; i < 2; ++i) {
            int flat = (t + i * 1024) * 4;          // element in 32x256 tile
            int row = flat >> 8, col = flat & 255;
            int e = ((row << 8) + col) ^ ((row & 15) << 3);
            unsigned int p01 = cvt_pk_bf16(vreg[i].x, vreg[i].y);
            unsigned int p23 = cvt_pk_bf16(vreg[i].z, vreg[i].w);
            ushort4 u;
            u.x = (unsigned short)p01; u.y = (unsigned short)(p01 >> 16);
            u.z = (unsigned short)p23; u.w = (unsigned short)(p23 >> 16);
            *reinterpret_cast<ushort4*>(&xa[cur][e]) = u;
        }

        // ---- issue NEXT tile's loads (full tile of compute covers latency) ----
        if (it < TPB - 1 && tile + 1 < NTILES) {
            const float4* xp = reinterpret_cast<const float4*>(x + (size_t)(tile + 1) * (BM * 256));
            #pragma unroll
            for (int i = 0; i < 2; ++i) vreg[i] = xp[t + i * 1024];
        }

        // ---- hoisted h1 inputs: issue batch + vc loads BEFORE GEMM1 (G1 covers) ----
        int bm0 = batch[r0 + lr];
        int bm1 = batch[r0 + 16 + lr];
        float4 vb0 = *reinterpret_cast<const float4*>(&vc[bm0 * 256 + c]);
        float4 vb1 = *reinterpret_cast<const float4*>(&vc[bm1 * 256 + c]);

        BAR_LGKM();   // xa[cur] visible to all waves

        // ---- GEMM1: D = W^slice . A  (transposed output) ----
        f32x4 acc[2];
        acc[0] = zero4; acc[1] = zero4;

        #pragma unroll
        for (int kk = 0; kk < 8; ++kk) {
            int kc = kk * 32 + lg * 8;
            short8 af[2];
            #pragma unroll
            for (int m = 0; m < 2; ++m) {
                int row = m * 16 + lr;
                int e = ((row << 8) + kc) ^ ((row & 15) << 3);
                af[m] = *reinterpret_cast<const short8*>(&xa[cur][e]);
            }
            acc[0] = __builtin_amdgcn_mfma_f32_16x16x32_bf16(w1r[kk], af[0], acc[0], 0, 0, 0);
            acc[1] = __builtin_amdgcn_mfma_f32_16x16x32_bf16(w1r[kk], af[1], acc[1], 0, 0, 0);
        }

        // ---- h1 = ssilu(acc + vc[b][c..c+3]) -> hb[cur] (one b64 write per frag) ----
        {
            int row0 = lr;
            float h0 = ssilu_f(acc[0][0] + vb0.x);
            float h1 = ssilu_f(acc[0][1] + vb0.y);
            float h2 = ssilu_f(acc[0][2] + vb0.z);
            float h3 = ssilu_f(acc[0][3] + vb0.w);
            uint2 pk;
            pk.x = cvt_pk_bf16(h0, h1);
            pk.y = cvt_pk_bf16(h2, h3);
            int e = ((row0 << 8) + c) ^ ((row0 & 15) << 3);
            *reinterpret_cast<uint2*>(&hb[cur][e]) = pk;
        }
        {
            int row1 = 16 + lr;
            float h0 = ssilu_f(acc[1][0] + vb1.x);
            float h1 = ssilu_f(acc[1][1] + vb1.y);
            float h2 = ssilu_f(acc[1][2] + vb1.z);
            float h3 = ssilu_f(acc[1][3] + vb1.w);
            uint2 pk;
            pk.x = cvt_pk_bf16(h0, h1);
            pk.y = cvt_pk_bf16(h2, h3);
            int e = ((row1 << 8) + c) ^ ((row1 & 15) << 3);
            *reinterpret_cast<uint2*>(&hb[cur][e]) = pk;
        }
        BAR_LGKM();   // hb[cur] visible; stores stay in flight

        // ---- GEMM2: D = W2^slice . H (transposed) ----
        acc[0] = zero4; acc[1] = zero4;

        #pragma unroll
        for (int kk = 0; kk < 8; ++kk) {
            int kc = kk * 32 + lg * 8;
            short8 af[2];
            #pragma unroll
            for (int m = 0; m < 2; ++m) {
                int row = m * 16 + lr;
                int e = ((row << 8) + kc) ^ ((row & 15) << 3);
                af[m] = *reinterpret_cast<const short8*>(&hb[cur][e]);
            }
            acc[0] = __builtin_amdgcn_mfma_f32_16x16x32_bf16(w2r[kk], af[0], acc[0], 0, 0, 0);
            acc[1] = __builtin_amdgcn_mfma_f32_16x16x32_bf16(w2r[kk], af[1], acc[1], 0, 0, 0);
        }

        // ---- epilogue: h = ssilu(acc+bn2) + x ; dwordx4 store + pooled partials ----
        #pragma unroll
        for (int m = 0; m < 2; ++m) {
            int row = m * 16 + lr;
            int bm = m ? bm1 : bm0;
            int e = ((row << 8) + c) ^ ((row & 15) << 3);
            ushort4 xv = *reinterpret_cast<const ushort4*>(&xa[cur][e]);
            float4 o;
            o.x = ssilu_f(acc[m][0] + bn2v.x) + bf2f(xv.x);
            o.y = ssilu_f(acc[m][1] + bn2v.y) + bf2f(xv.y);
            o.z = ssilu_f(acc[m][2] + bn2v.z) + bf2f(xv.z);
            o.w = ssilu_f(acc[m][3] + bn2v.w) + bf2f(xv.w);
            *reinterpret_cast<float4*>(&hout[(size_t)(r0 + row) * 256 + c]) = o;
            if (!blk_multi) {             // uniform branch: whole block one graph (~96%)
                pa[0] += o.x; pa[1] += o.y; pa[2] += o.z; pa[3] += o.w;
            } else {
                bool ing0 = (bm == g0);
                pa[0] += ing0 ? o.x : 0.f;  pb[0] += ing0 ? 0.f : o.x;
                pa[1] += ing0 ? o.y : 0.f;  pb[1] += ing0 ? 0.f : o.y;
                pa[2] += ing0 ? o.z : 0.f;  pb[2] += ing0 ? 0.f : o.z;
                pa[3] += ing0 ? o.w : 0.f;  pb[3] += ing0 ? 0.f : o.w;
            }
        }
        // no end-of-tile barrier: next tile uses the other buffers; rewrite of
        // xa[cur]/hb[cur] happens ≥2 barriers later, after all waves' reads retired
        cur ^= 1;
    }

    // ---- pooled partial: reduce over the 16 lr lanes, one atomic per col ----
    #pragma unroll
    for (int r = 0; r < 4; ++r) {
        float p = pa[r];
        p += __shfl_xor(p, 1);
        p += __shfl_xor(p, 2);
        p += __shfl_xor(p, 4);
        p += __shfl_xor(p, 8);
        if (lr == 0) atomicAdd(&sums[g0 * 256 + c + r], p);
    }
    if (blk_multi) {
        #pragma unroll
        for (int r = 0; r < 4; ++r) {
            float q = pb[r];
            q += __shfl_xor(q, 1);
            q += __shfl_xor(q, 2);
            q += __shfl_xor(q, 4);
            q += __shfl_xor(q, 8);
            if (lr == 0 && g0 + 1 < NGRAPH) atomicAdd(&sums[(g0 + 1) * 256 + c + r], q);
        }
    }
}

// ---- fused virtual-node MLP, 4-way K-split per block (latency cut) ----
__global__ __launch_bounds__(1024) void vmlp(
        const float* __restrict__ sums, const int* __restrict__ counts,
        const float* __restrict__ vx, const float* __restrict__ Wv1,
        const float* __restrict__ bv1, const float* __restrict__ Wv2,
        const float* __restrict__ bv2, float* __restrict__ out) {
    __shared__ float cat[512];
    __shared__ float psum[4][256];
    __shared__ float vsh[256];
    const int b = blockIdx.x, t = threadIdx.x;
    const int col = t & 255;
    const int seg = t >> 8;           // 0..3

    if (t < 512) {
        if (t < 256) {
            float cnt = fmaxf((float)counts[b], 1.0f);
            cat[t] = sums[b * 256 + t] / cnt;
        } else {
            cat[t] = vx[b * 256 + (t - 256)];
        }
    }
    __syncthreads();

    // layer 1: each seg accumulates 128 of the 512 k's
    float a = 0.f;
    #pragma unroll 8
    for (int k = seg * 128; k < seg * 128 + 128; ++k)
        a = fmaf(cat[k], Wv1[k * 256 + col], a);
    psum[seg][col] = a;
    __syncthreads();
    if (t < 256) {
        float s = (psum[0][t] + psum[1][t]) + (psum[2][t] + psum[3][t]);
        vsh[t] = ssilu_f(s + bv1[t]);
    }
    __syncthreads();

    // layer 2: each seg accumulates 64 of the 256 k's
    float a2 = 0.f;
    #pragma unroll 8
    for (int k = seg * 64; k < seg * 64 + 64; ++k)
        a2 = fmaf(vsh[k], Wv2[k * 256 + col], a2);
    psum[seg][col] = a2;
    __syncthreads();
    if (t < 256) {
        float s = (psum[0][t] + psum[1][t]) + (psum[2][t] + psum[3][t]);
        out[b * 256 + t] = ssilu_f(s + bv2[t]);
    }
}

extern "C" void kernel_launch(void* const* d_in, const int* in_sizes, int n_in,
                              void* d_out, int out_size, void* d_ws, size_t ws_size,
                              hipStream_t stream) {
    const float* x   = (const float*)d_in[0];
    const int*   batch = (const int*)d_in[1];
    const float* vx  = (const float*)d_in[2];
    const float* Wn1 = (const float*)d_in[3];
    const float* bn1 = (const float*)d_in[4];
    const float* Wn2 = (const float*)d_in[5];
    const float* bn2 = (const float*)d_in[6];
    const float* Wv1 = (const float*)d_in[7];
    const float* bv1 = (const float*)d_in[8];
    const float* Wv2 = (const float*)d_in[9];
    const float* bv2 = (const float*)d_in[10];

    float* hout = (float*)d_out;
    float* vout = hout + (size_t)N_ROWS * 256;

    // ws layout — total 393,472 B
    char* ws = (char*)d_ws;
    unsigned short* wnt1x  = (unsigned short*)(ws);           // 256*256*2 = 131072
    unsigned short* wnt2   = (unsigned short*)(ws + 131072);  // 131072
    float*          vc     = (float*)(ws + 262144);           // 64*256*4  = 65536
    float*          sums   = (float*)(ws + 327680);           // 65536
    int*            counts = (int*)(ws + 393216);             // 256

    setup_kernel<<<32 + 2 * NGRAPH, 256, 0, stream>>>(Wn1, Wn2, vx, bn1, batch,
                                                      wnt1x, wnt2, vc, sums, counts);
    node_kernel<<<NBLK, 1024, 0, stream>>>(x, batch, wnt1x, vc, wnt2, bn2, hout, sums);
    vmlp<<<NGRAPH, 1024, 0, stream>>>(sums, counts, vx, Wv1, bv1, Wv2, bv2, vout);
}

// Round 23
// 209.537 us; speedup vs baseline: 1.2547x; 1.2547x over previous
//
#include <hip/hip_runtime.h>
#include <hip/hip_bf16.h>

#define N_ROWS 200000
#define BM 32
#define NTILES 6250
#define TPB 4
#define NBLK ((NTILES + TPB - 1) / TPB)
#define NGRAPH 64
#define SSCALE 1.6666666666666667f
#define LOG2E 1.4426950408889634f

typedef __attribute__((ext_vector_type(8))) short short8;   // 8 bf16 (4 VGPRs)
typedef __attribute__((ext_vector_type(4))) float f32x4;    // MFMA C/D frag

__device__ __forceinline__ unsigned short f2bf(float f) {
    unsigned int u = __float_as_uint(f);
    u = (u + 0x7fffu + ((u >> 16) & 1u)) >> 16;   // RNE
    return (unsigned short)u;
}
__device__ __forceinline__ float bf2f(unsigned short v) {
    return __uint_as_float(((unsigned int)v) << 16);
}
__device__ __forceinline__ unsigned int cvt_pk_bf16(float lo, float hi) {
    unsigned int r;
    asm("v_cvt_pk_bf16_f32 %0, %1, %2" : "=v"(r) : "v"(lo), "v"(hi));
    return r;
}
// fast ScaledSiLU: s*SCALE * rcp(1 + exp2(-s*log2e))
__device__ __forceinline__ float ssilu_f(float s) {
    float e = __builtin_amdgcn_exp2f(-s * LOG2E);
    return s * SSCALE * __builtin_amdgcn_rcpf(1.0f + e);
}

// lgkmcnt-only barrier: LDS ops retired, global stores stay in flight
#define BAR_LGKM()  do { asm volatile("s_waitcnt lgkmcnt(0)" ::: "memory"); \
                         __builtin_amdgcn_s_barrier(); } while (0)

// ---- fused setup: LDS-tiled weight transpose x2, vc GEMV, sums zero + counts ----
__global__ __launch_bounds__(256) void setup_kernel(
        const float* __restrict__ Wn1, const float* __restrict__ Wn2,
        const float* __restrict__ vx, const float* __restrict__ bn1,
        const int* __restrict__ batch,
        unsigned short* __restrict__ wnt1x, unsigned short* __restrict__ wnt2,
        float* __restrict__ vc, float* __restrict__ sums,
        int* __restrict__ counts) {
    const int bid = blockIdx.x;
    const int t = threadIdx.x;
    if (bid < 32) {
        const float* W = (bid < 16) ? Wn1 : Wn2;
        unsigned short* out = (bid < 16) ? wnt1x : wnt2;
        const int tile = bid & 15;
        const int bi = (tile >> 2) * 64;   // k base
        const int bj = (tile & 3) * 64;    // n base
        __shared__ float lds[64][65];
        const int rr = t >> 4;             // 0..15
        const int cc = (t & 15) * 4;       // 0..60
        #pragma unroll
        for (int i = 0; i < 4; ++i) {
            int row = i * 16 + rr;         // k offset
            float4 v = *reinterpret_cast<const float4*>(&W[(bi + row) * 256 + bj + cc]);
            lds[row][cc] = v.x; lds[row][cc + 1] = v.y;
            lds[row][cc + 2] = v.z; lds[row][cc + 3] = v.w;
        }
        __syncthreads();
        #pragma unroll
        for (int i = 0; i < 4; ++i) {
            int nrow = i * 16 + rr;        // n offset
            ushort4 u;
            u.x = f2bf(lds[cc + 0][nrow]);
            u.y = f2bf(lds[cc + 1][nrow]);
            u.z = f2bf(lds[cc + 2][nrow]);
            u.w = f2bf(lds[cc + 3][nrow]);
            *reinterpret_cast<ushort4*>(&out[(bj + nrow) * 256 + bi + cc]) = u;
        }
    } else if (bid < 32 + NGRAPH) {
        int b = bid - 32;
        __shared__ float vrow[256];
        vrow[t] = vx[b * 256 + t];
        __syncthreads();
        float a = bn1[t];
        #pragma unroll 8
        for (int k = 0; k < 256; ++k) a = fmaf(vrow[k], Wn1[(256 + k) * 256 + t], a);
        vc[b * 256 + t] = a;
    } else {
        int b = bid - 32 - NGRAPH;
        sums[b * 256 + t] = 0.0f;
        if (t == 0) {
            int lo = 0, hi = N_ROWS;
            while (lo < hi) { int m = (lo + hi) >> 1; if (batch[m] < b) lo = m + 1; else hi = m; }
            int lb = lo;
            lo = 0; hi = N_ROWS;
            while (lo < hi) { int m = (lo + hi) >> 1; if (batch[m] < b + 1) lo = m + 1; else hi = m; }
            counts[b] = lo - lb;
        }
    }
}

// ---- main fused node-MLP kernel: 16 waves x 16 cols, 64 weight regs/thread,
//      transposed mfma output, 16-row XOR swizzle; TPB=4 (empirical optimum) ----
__global__ __launch_bounds__(1024, 4) void node_kernel(
    const float* __restrict__ x, const int* __restrict__ batch,
    const unsigned short* __restrict__ wnt1x,  // [256][256] bf16, x-half of Wn1, N-major
    const float* __restrict__ vc,              // [64][256] per-graph bias (incl bn1)
    const unsigned short* __restrict__ wnt2,   // [256][256] bf16, N-major
    const float* __restrict__ bn2,
    float* __restrict__ hout, float* __restrict__ sums)
{
    __shared__ unsigned short xa[2][BM * 256]; // x tiles bf16, swizzled (2x16 KB)
    __shared__ unsigned short hb[2][BM * 256]; // h1 tiles bf16, swizzled (2x16 KB)

    const int t = threadIdx.x;
    const int lane = t & 63;
    const int wave = t >> 6;          // 0..15
    const int lr = lane & 15;
    const int lg = lane >> 4;
    const int c = wave * 16 + lg * 4; // this lane's 4 output cols: c..c+3

    // ---- weight slices into registers (A-operand layout: lane&15 = weight col) ----
    short8 w1r[8], w2r[8];
    #pragma unroll
    for (int kk = 0; kk < 8; ++kk) {
        int off = (wave * 16 + lr) * 256 + kk * 32 + lg * 8;
        w1r[kk] = *reinterpret_cast<const short8*>(&wnt1x[off]);
        w2r[kk] = *reinterpret_cast<const short8*>(&wnt2[off]);
    }
    const float4 bn2v = *reinterpret_cast<const float4*>(&bn2[c]);

    const int tile0 = blockIdx.x * TPB;
    const int blk_r0 = tile0 * BM;
    const int blk_rlast = min(blk_r0 + TPB * BM, N_ROWS) - 1;
    const int g0 = batch[blk_r0];
    const bool blk_multi = (batch[blk_rlast] != g0);
    float pa[4] = {0.f, 0.f, 0.f, 0.f};   // pooled partials: graph g0
    float pb[4] = {0.f, 0.f, 0.f, 0.f};   // pooled partials: graph g0+1

    const f32x4 zero4 = {0.f, 0.f, 0.f, 0.f};

    // ---- prologue: load tile0's x into regs (32x256 f32 = 1024 thr x 2 float4) ----
    float4 vreg[2];
    {
        const float4* xp = reinterpret_cast<const float4*>(x + (size_t)tile0 * (BM * 256));
        #pragma unroll
        for (int i = 0; i < 2; ++i) vreg[i] = xp[t + i * 1024];
    }

    int cur = 0;
    #pragma unroll 1
    for (int it = 0; it < TPB; ++it) {
        const int tile = tile0 + it;
        if (tile >= NTILES) break;
        const int r0 = tile * BM;

        // ---- write staged regs -> xa[cur] as bf16 (16-row swizzle) ----
        #pragma unroll
        for (int i = 0; i < 2; ++i) {
            int flat = (t + i * 1024) * 4;          // element in 32x256 tile
            int row = flat >> 8, col = flat & 255;
            int e = ((row << 8) + col) ^ ((row & 15) << 3);
            unsigned int p01 = cvt_pk_bf16(vreg[i].x, vreg[i].y);
            unsigned int p23 = cvt_pk_bf16(vreg[i].z, vreg[i].w);
            ushort4 u;
            u.x = (unsigned short)p01; u.y = (unsigned short)(p01 >> 16);
            u.z = (unsigned short)p23; u.w = (unsigned short)(p23 >> 16);
            *reinterpret_cast<ushort4*>(&xa[cur][e]) = u;
        }

        // ---- issue NEXT tile's loads (full tile of compute covers latency) ----
        if (it < TPB - 1 && tile + 1 < NTILES) {
            const float4* xp = reinterpret_cast<const float4*>(x + (size_t)(tile + 1) * (BM * 256));
            #pragma unroll
            for (int i = 0; i < 2; ++i) vreg[i] = xp[t + i * 1024];
        }

        BAR_LGKM();   // xa[cur] visible to all waves

        // ---- GEMM1: D = W^slice . A  (transposed output) ----
        f32x4 acc[2];
        acc[0] = zero4; acc[1] = zero4;

        #pragma unroll
        for (int kk = 0; kk < 8; ++kk) {
            int kc = kk * 32 + lg * 8;
            short8 af[2];
            #pragma unroll
            for (int m = 0; m < 2; ++m) {
                int row = m * 16 + lr;
                int e = ((row << 8) + kc) ^ ((row & 15) << 3);
                af[m] = *reinterpret_cast<const short8*>(&xa[cur][e]);
            }
            acc[0] = __builtin_amdgcn_mfma_f32_16x16x32_bf16(w1r[kk], af[0], acc[0], 0, 0, 0);
            acc[1] = __builtin_amdgcn_mfma_f32_16x16x32_bf16(w1r[kk], af[1], acc[1], 0, 0, 0);
        }

        // ---- h1 = ssilu(acc + vc[b][c..c+3]) -> hb[cur] (one b64 write per frag) ----
        int bm0 = batch[r0 + lr];
        int bm1 = batch[r0 + 16 + lr];
        #pragma unroll
        for (int m = 0; m < 2; ++m) {
            int row = m * 16 + lr;
            int bm = m ? bm1 : bm0;
            float4 vb = *reinterpret_cast<const float4*>(&vc[bm * 256 + c]);
            float h0 = ssilu_f(acc[m][0] + vb.x);
            float h1 = ssilu_f(acc[m][1] + vb.y);
            float h2 = ssilu_f(acc[m][2] + vb.z);
            float h3 = ssilu_f(acc[m][3] + vb.w);
            uint2 pk;
            pk.x = cvt_pk_bf16(h0, h1);
            pk.y = cvt_pk_bf16(h2, h3);
            int e = ((row << 8) + c) ^ ((row & 15) << 3);
            *reinterpret_cast<uint2*>(&hb[cur][e]) = pk;
        }
        BAR_LGKM();   // hb[cur] visible; stores stay in flight

        // ---- GEMM2: D = W2^slice . H (transposed) ----
        acc[0] = zero4; acc[1] = zero4;

        #pragma unroll
        for (int kk = 0; kk < 8; ++kk) {
            int kc = kk * 32 + lg * 8;
            short8 af[2];
            #pragma unroll
            for (int m = 0; m < 2; ++m) {
                int row = m * 16 + lr;
                int e = ((row << 8) + kc) ^ ((row & 15) << 3);
                af[m] = *reinterpret_cast<const short8*>(&hb[cur][e]);
            }
            acc[0] = __builtin_amdgcn_mfma_f32_16x16x32_bf16(w2r[kk], af[0], acc[0], 0, 0, 0);
            acc[1] = __builtin_amdgcn_mfma_f32_16x16x32_bf16(w2r[kk], af[1], acc[1], 0, 0, 0);
        }

        // ---- epilogue: h = ssilu(acc+bn2) + x ; dwordx4 store + pooled partials ----
        #pragma unroll
        for (int m = 0; m < 2; ++m) {
            int row = m * 16 + lr;
            int bm = m ? bm1 : bm0;
            int e = ((row << 8) + c) ^ ((row & 15) << 3);
            ushort4 xv = *reinterpret_cast<const ushort4*>(&xa[cur][e]);
            float4 o;
            o.x = ssilu_f(acc[m][0] + bn2v.x) + bf2f(xv.x);
            o.y = ssilu_f(acc[m][1] + bn2v.y) + bf2f(xv.y);
            o.z = ssilu_f(acc[m][2] + bn2v.z) + bf2f(xv.z);
            o.w = ssilu_f(acc[m][3] + bn2v.w) + bf2f(xv.w);
            *reinterpret_cast<float4*>(&hout[(size_t)(r0 + row) * 256 + c]) = o;
            bool ing0 = (bm == g0);
            pa[0] += ing0 ? o.x : 0.f;  pb[0] += ing0 ? 0.f : o.x;
            pa[1] += ing0 ? o.y : 0.f;  pb[1] += ing0 ? 0.f : o.y;
            pa[2] += ing0 ? o.z : 0.f;  pb[2] += ing0 ? 0.f : o.z;
            pa[3] += ing0 ? o.w : 0.f;  pb[3] += ing0 ? 0.f : o.w;
        }
        // no end-of-tile barrier: next tile uses the other buffers; rewrite of
        // xa[cur]/hb[cur] happens ≥2 barriers later, after all waves' reads retired
        cur ^= 1;
    }

    // ---- pooled partial: reduce over the 16 lr lanes, one atomic per col ----
    #pragma unroll
    for (int r = 0; r < 4; ++r) {
        float p = pa[r];
        p += __shfl_xor(p, 1);
        p += __shfl_xor(p, 2);
        p += __shfl_xor(p, 4);
        p += __shfl_xor(p, 8);
        if (lr == 0) atomicAdd(&sums[g0 * 256 + c + r], p);
    }
    if (blk_multi) {
        #pragma unroll
        for (int r = 0; r < 4; ++r) {
            float q = pb[r];
            q += __shfl_xor(q, 1);
            q += __shfl_xor(q, 2);
            q += __shfl_xor(q, 4);
            q += __shfl_xor(q, 8);
            if (lr == 0 && g0 + 1 < NGRAPH) atomicAdd(&sums[(g0 + 1) * 256 + c + r], q);
        }
    }
}

// ---- fused virtual-node MLP, 4-way K-split per block (latency cut) ----
// 64 blocks x 1024 thr: col = t&255, seg = t>>8 (4 K-segments), LDS tree-combine
__global__ __launch_bounds__(1024) void vmlp(
        const float* __restrict__ sums, const int* __restrict__ counts,
        const float* __restrict__ vx, const float* __restrict__ Wv1,
        const float* __restrict__ bv1, const float* __restrict__ Wv2,
        const float* __restrict__ bv2, float* __restrict__ out) {
    __shared__ float cat[512];
    __shared__ float psum[4][256];
    __shared__ float vsh[256];
    const int b = blockIdx.x, t = threadIdx.x;
    const int col = t & 255;
    const int seg = t >> 8;           // 0..3

    if (t < 512) {
        if (t < 256) {
            float cnt = fmaxf((float)counts[b], 1.0f);
            cat[t] = sums[b * 256 + t] / cnt;
        } else {
            cat[t] = vx[b * 256 + (t - 256)];
        }
    }
    __syncthreads();

    // layer 1: each seg accumulates 128 of the 512 k's
    float a = 0.f;
    #pragma unroll 8
    for (int k = seg * 128; k < seg * 128 + 128; ++k)
        a = fmaf(cat[k], Wv1[k * 256 + col], a);
    psum[seg][col] = a;
    __syncthreads();
    if (t < 256) {
        float s = (psum[0][t] + psum[1][t]) + (psum[2][t] + psum[3][t]);
        vsh[t] = ssilu_f(s + bv1[t]);
    }
    __syncthreads();

    // layer 2: each seg accumulates 64 of the 256 k's
    float a2 = 0.f;
    #pragma unroll 8
    for (int k = seg * 64; k < seg * 64 + 64; ++k)
        a2 = fmaf(vsh[k], Wv2[k * 256 + col], a2);
    psum[seg][col] = a2;
    __syncthreads();
    if (t < 256) {
        float s = (psum[0][t] + psum[1][t]) + (psum[2][t] + psum[3][t]);
        out[b * 256 + t] = ssilu_f(s + bv2[t]);
    }
}

extern "C" void kernel_launch(void* const* d_in, const int* in_sizes, int n_in,
                              void* d_out, int out_size, void* d_ws, size_t ws_size,
                              hipStream_t stream) {
    const float* x   = (const float*)d_in[0];
    const int*   batch = (const int*)d_in[1];
    const float* vx  = (const float*)d_in[2];
    const float* Wn1 = (const float*)d_in[3];
    const float* bn1 = (const float*)d_in[4];
    const float* Wn2 = (const float*)d_in[5];
    const float* bn2 = (const float*)d_in[6];
    const float* Wv1 = (const float*)d_in[7];
    const float* bv1 = (const float*)d_in[8];
    const float* Wv2 = (const float*)d_in[9];
    const float* bv2 = (const float*)d_in[10];

    float* hout = (float*)d_out;
    float* vout = hout + (size_t)N_ROWS * 256;

    // ws layout — total 393,472 B
    char* ws = (char*)d_ws;
    unsigned short* wnt1x  = (unsigned short*)(ws);           // 256*256*2 = 131072
    unsigned short* wnt2   = (unsigned short*)(ws + 131072);  // 131072
    float*          vc     = (float*)(ws + 262144);           // 64*256*4  = 65536
    float*          sums   = (float*)(ws + 327680);           // 65536
    int*            counts = (int*)(ws + 393216);             // 256

    setup_kernel<<<32 + 2 * NGRAPH, 256, 0, stream>>>(Wn1, Wn2, vx, bn1, batch,
                                                      wnt1x, wnt2, vc, sums, counts);
    node_kernel<<<NBLK, 1024, 0, stream>>>(x, batch, wnt1x, vc, wnt2, bn2, hout, sums);
    vmlp<<<NGRAPH, 1024, 0, stream>>>(sums, counts, vx, Wv1, bv1, Wv2, bv2, vout);
}